// Round 1
// baseline (119.009 us; speedup 1.0000x reference)
//
#include <hip/hip_runtime.h>
#include <math.h>

#define IMG_W 512
#define IMG_H 512
#define TILE_ROWS 16   // output rows per block
#define ROWS_PT 8      // rows per thread (2 row-strips of 128 float4-cols each)
#define EPS16 1.6e-3f  // 16 * 1e-4, since gx/gy carried unscaled (x4)

// One row's worth of this thread's window: 4 center cols + left/right taps.
struct RowWin {
    float l;              // col 4*cf - 1
    float m0, m1, m2, m3; // cols 4*cf .. 4*cf+3
    float r;              // col 4*cf + 4
};

__device__ __forceinline__ RowWin load_row(const float* __restrict__ img,
                                           int r, int cf) {
    RowWin w;
    if (r < 0 || r >= IMG_H) {
        w.l = w.m0 = w.m1 = w.m2 = w.m3 = w.r = 0.f;
        return w;
    }
    const float* p = img + (size_t)r * IMG_W + 4 * cf;
    float4 v = *reinterpret_cast<const float4*>(p);
    w.m0 = v.x; w.m1 = v.y; w.m2 = v.z; w.m3 = v.w;
    w.l = (cf > 0)              ? p[-1] : 0.f;   // zero pad left image edge
    w.r = (cf < IMG_W / 4 - 1)  ? p[4]  : 0.f;   // zero pad right image edge
    return w;
}

__global__ __launch_bounds__(256) void sobel_kernel(const float* __restrict__ x,
                                                    float* __restrict__ out) {
    const int tid  = threadIdx.x;
    const int cf   = tid & 127;   // float4 column index, 0..127 (covers 512 cols)
    const int half = tid >> 7;    // which 8-row strip of the 16-row tile
    const int r0   = blockIdx.x * TILE_ROWS + half * ROWS_PT;

    const float* img = x   + (size_t)blockIdx.y * (IMG_H * IMG_W);
    float*       o   = out + (size_t)blockIdx.y * (IMG_H * IMG_W);

    RowWin A = load_row(img, r0 - 1, cf);  // row r-1
    RowWin B = load_row(img, r0,     cf);  // row r

    for (int i = 0; i < ROWS_PT; ++i) {
        const int r = r0 + i;
        RowWin C = load_row(img, r + 1, cf);  // row r+1

        // vertical smooth s = A + 2B + C, vertical diff d = A - C (6 cols each)
        float sl = A.l  + 2.f * B.l  + C.l;
        float s0 = A.m0 + 2.f * B.m0 + C.m0;
        float s1 = A.m1 + 2.f * B.m1 + C.m1;
        float s2 = A.m2 + 2.f * B.m2 + C.m2;
        float s3 = A.m3 + 2.f * B.m3 + C.m3;
        float sr = A.r  + 2.f * B.r  + C.r;

        float dl = A.l  - C.l;
        float d0 = A.m0 - C.m0;
        float d1 = A.m1 - C.m1;
        float d2 = A.m2 - C.m2;
        float d3 = A.m3 - C.m3;
        float dr = A.r  - C.r;

        // gx*4 = s[j-1] - s[j+1];  gy*4 = d[j-1] + 2 d[j] + d[j+1]
        float gx0 = sl - s1, gx1 = s0 - s2, gx2 = s1 - s3, gx3 = s2 - sr;
        float gy0 = dl + 2.f * d0 + d1;
        float gy1 = d0 + 2.f * d1 + d2;
        float gy2 = d1 + 2.f * d2 + d3;
        float gy3 = d2 + 2.f * d3 + dr;

        // out = sqrt(gx^2+gy^2+eps) = 0.25*sqrt((4gx)^2+(4gy)^2+16eps)
        float4 res;
        res.x = 0.25f * sqrtf(gx0 * gx0 + gy0 * gy0 + EPS16);
        res.y = 0.25f * sqrtf(gx1 * gx1 + gy1 * gy1 + EPS16);
        res.z = 0.25f * sqrtf(gx2 * gx2 + gy2 * gy2 + EPS16);
        res.w = 0.25f * sqrtf(gx3 * gx3 + gy3 * gy3 + EPS16);

        *reinterpret_cast<float4*>(o + (size_t)r * IMG_W + 4 * cf) = res;

        // slide the window down one row
        A = B; B = C;
    }
}

extern "C" void kernel_launch(void* const* d_in, const int* in_sizes, int n_in,
                              void* d_out, int out_size, void* d_ws, size_t ws_size,
                              hipStream_t stream) {
    const float* x = (const float*)d_in[0];
    float* out = (float*)d_out;
    const int batch = in_sizes[0] / (IMG_H * IMG_W);  // 64
    dim3 grid(IMG_H / TILE_ROWS, batch);              // (32, 64) = 2048 blocks
    sobel_kernel<<<grid, 256, 0, stream>>>(x, out);
}

// Round 2
// 113.604 us; speedup vs baseline: 1.0476x; 1.0476x over previous
//
#include <hip/hip_runtime.h>
#include <math.h>

#define IMG_W 512
#define IMG_H 512
#define ROWS_PT 8                         // rows per thread (sliding window)
#define WAVES_PER_BLOCK 4
#define TILE_ROWS (ROWS_PT * WAVES_PER_BLOCK)   // 32 rows per block
#define EPS16 1.6e-3f                     // 16 * 1e-4 (gx,gy carried x4)

// One wave covers a full 512-col row: lane owns cols [4L,4L+4) and [256+4L, 256+4L+4).
struct Row {
    float4 a;              // cols 4*lane .. 4*lane+3
    float4 b;              // cols 256+4*lane .. 256+4*lane+3
    float la, ra, lb, rb;  // horizontal halo taps (via shfl)
};

__device__ __forceinline__ Row load_row(const float* __restrict__ img, int r, int lane) {
    Row w;
    if (r < 0 || r >= IMG_H) {            // wave-uniform branch (zero padding)
        w.a = make_float4(0.f, 0.f, 0.f, 0.f);
        w.b = make_float4(0.f, 0.f, 0.f, 0.f);
        w.la = w.ra = w.lb = w.rb = 0.f;
        return w;
    }
    const float* p = img + (size_t)r * IMG_W + 4 * lane;
    w.a = *reinterpret_cast<const float4*>(p);        // contiguous 1KB per wave
    w.b = *reinterpret_cast<const float4*>(p + 256);  // contiguous 1KB per wave
    float c255 = __shfl(w.a.w, 63);       // col 255 (for half-b left tap of lane 0)
    float c256 = __shfl(w.b.x, 0);        // col 256 (for half-a right tap of lane 63)
    w.la = __shfl_up(w.a.w, 1);           // col 4L-1
    w.ra = __shfl_down(w.a.x, 1);         // col 4L+4
    w.lb = __shfl_up(w.b.w, 1);           // col 256+4L-1
    w.rb = __shfl_down(w.b.x, 1);         // col 256+4L+4
    if (lane == 0)  { w.la = 0.f;  w.lb = c255; }   // image left edge zero-pad
    if (lane == 63) { w.ra = c256; w.rb = 0.f;  }   // image right edge zero-pad
    return w;
}

__device__ __forceinline__ float4 sobel_half(const float4& A, float Al, float Ar,
                                             const float4& B, float Bl, float Br,
                                             const float4& C, float Cl, float Cr) {
    // vertical smooth s = A + 2B + C; vertical diff d = A - C (6 cols)
    float sl = Al  + 2.f * Bl  + Cl;
    float s0 = A.x + 2.f * B.x + C.x;
    float s1 = A.y + 2.f * B.y + C.y;
    float s2 = A.z + 2.f * B.z + C.z;
    float s3 = A.w + 2.f * B.w + C.w;
    float sr = Ar  + 2.f * Br  + Cr;

    float dl = Al  - Cl;
    float d0 = A.x - C.x;
    float d1 = A.y - C.y;
    float d2 = A.z - C.z;
    float d3 = A.w - C.w;
    float dr = Ar  - Cr;

    // gx*4 = s[j-1] - s[j+1];  gy*4 = d[j-1] + 2 d[j] + d[j+1]
    float gx0 = sl - s1, gx1 = s0 - s2, gx2 = s1 - s3, gx3 = s2 - sr;
    float gy0 = dl + 2.f * d0 + d1;
    float gy1 = d0 + 2.f * d1 + d2;
    float gy2 = d1 + 2.f * d2 + d3;
    float gy3 = d2 + 2.f * d3 + dr;

    float4 res;
    res.x = 0.25f * sqrtf(gx0 * gx0 + gy0 * gy0 + EPS16);
    res.y = 0.25f * sqrtf(gx1 * gx1 + gy1 * gy1 + EPS16);
    res.z = 0.25f * sqrtf(gx2 * gx2 + gy2 * gy2 + EPS16);
    res.w = 0.25f * sqrtf(gx3 * gx3 + gy3 * gy3 + EPS16);
    return res;
}

__global__ __launch_bounds__(256) void sobel_kernel(const float* __restrict__ x,
                                                    float* __restrict__ out) {
    const int lane = threadIdx.x & 63;
    const int wave = threadIdx.x >> 6;
    const int r0   = blockIdx.x * TILE_ROWS + wave * ROWS_PT;

    const float* img = x   + (size_t)blockIdx.y * (IMG_H * IMG_W);
    float*       o   = out + (size_t)blockIdx.y * (IMG_H * IMG_W);

    Row A = load_row(img, r0 - 1, lane);
    Row B = load_row(img, r0,     lane);

#pragma unroll
    for (int i = 0; i < ROWS_PT; ++i) {
        const int r = r0 + i;
        Row C = load_row(img, r + 1, lane);

        float4 ra = sobel_half(A.a, A.la, A.ra, B.a, B.la, B.ra, C.a, C.la, C.ra);
        float4 rb = sobel_half(A.b, A.lb, A.rb, B.b, B.lb, B.rb, C.b, C.lb, C.rb);

        float* po = o + (size_t)r * IMG_W + 4 * lane;
        *reinterpret_cast<float4*>(po)       = ra;   // contiguous 1KB per wave
        *reinterpret_cast<float4*>(po + 256) = rb;   // contiguous 1KB per wave

        A = B; B = C;   // slide window down one row
    }
}

extern "C" void kernel_launch(void* const* d_in, const int* in_sizes, int n_in,
                              void* d_out, int out_size, void* d_ws, size_t ws_size,
                              hipStream_t stream) {
    const float* x = (const float*)d_in[0];
    float* out = (float*)d_out;
    const int batch = in_sizes[0] / (IMG_H * IMG_W);   // 64
    dim3 grid(IMG_H / TILE_ROWS, batch);               // (16, 64) = 1024 blocks
    sobel_kernel<<<grid, 256, 0, stream>>>(x, out);
}

// Round 4
// 113.316 us; speedup vs baseline: 1.0502x; 1.0025x over previous
//
#include <hip/hip_runtime.h>
#include <math.h>

#define IMG_W 512
#define IMG_H 512
#define ROWS_PT 4                         // rows per thread (sliding window)
#define WAVES_PER_BLOCK 4
#define TILE_ROWS (ROWS_PT * WAVES_PER_BLOCK)   // 16 rows per block
#define EPS16 1.6e-3f                     // 16 * 1e-4 (gx,gy carried x4)

typedef float vfloat4 __attribute__((ext_vector_type(4)));  // native vec for nt-store

// One wave covers a full 512-col row: lane owns cols [4L,4L+4) and [256+4L, 256+4L+4).
struct Row {
    float4 a;              // cols 4*lane .. 4*lane+3
    float4 b;              // cols 256+4*lane .. 256+4*lane+3
    float la, ra, lb, rb;  // horizontal halo taps (via shfl)
};

__device__ __forceinline__ Row load_row(const float* __restrict__ img, int r, int lane) {
    Row w;
    if (r < 0 || r >= IMG_H) {            // wave-uniform branch (zero padding)
        w.a = make_float4(0.f, 0.f, 0.f, 0.f);
        w.b = make_float4(0.f, 0.f, 0.f, 0.f);
        w.la = w.ra = w.lb = w.rb = 0.f;
        return w;
    }
    const float* p = img + (size_t)r * IMG_W + 4 * lane;
    w.a = *reinterpret_cast<const float4*>(p);        // contiguous 1KB per wave
    w.b = *reinterpret_cast<const float4*>(p + 256);  // contiguous 1KB per wave
    float c255 = __shfl(w.a.w, 63);       // col 255 (half-b left tap of lane 0)
    float c256 = __shfl(w.b.x, 0);        // col 256 (half-a right tap of lane 63)
    w.la = __shfl_up(w.a.w, 1);           // col 4L-1
    w.ra = __shfl_down(w.a.x, 1);         // col 4L+4
    w.lb = __shfl_up(w.b.w, 1);           // col 256+4L-1
    w.rb = __shfl_down(w.b.x, 1);         // col 256+4L+4
    if (lane == 0)  { w.la = 0.f;  w.lb = c255; }   // image left edge zero-pad
    if (lane == 63) { w.ra = c256; w.rb = 0.f;  }   // image right edge zero-pad
    return w;
}

__device__ __forceinline__ vfloat4 sobel_half(const float4& A, float Al, float Ar,
                                              const float4& B, float Bl, float Br,
                                              const float4& C, float Cl, float Cr) {
    // vertical smooth s = A + 2B + C; vertical diff d = A - C (6 cols)
    float sl = Al  + 2.f * Bl  + Cl;
    float s0 = A.x + 2.f * B.x + C.x;
    float s1 = A.y + 2.f * B.y + C.y;
    float s2 = A.z + 2.f * B.z + C.z;
    float s3 = A.w + 2.f * B.w + C.w;
    float sr = Ar  + 2.f * Br  + Cr;

    float dl = Al  - Cl;
    float d0 = A.x - C.x;
    float d1 = A.y - C.y;
    float d2 = A.z - C.z;
    float d3 = A.w - C.w;
    float dr = Ar  - Cr;

    // gx*4 = s[j-1] - s[j+1];  gy*4 = d[j-1] + 2 d[j] + d[j+1]
    float gx0 = sl - s1, gx1 = s0 - s2, gx2 = s1 - s3, gx3 = s2 - sr;
    float gy0 = dl + 2.f * d0 + d1;
    float gy1 = d0 + 2.f * d1 + d2;
    float gy2 = d1 + 2.f * d2 + d3;
    float gy3 = d2 + 2.f * d3 + dr;

    vfloat4 res;
    res.x = 0.25f * sqrtf(gx0 * gx0 + gy0 * gy0 + EPS16);
    res.y = 0.25f * sqrtf(gx1 * gx1 + gy1 * gy1 + EPS16);
    res.z = 0.25f * sqrtf(gx2 * gx2 + gy2 * gy2 + EPS16);
    res.w = 0.25f * sqrtf(gx3 * gx3 + gy3 * gy3 + EPS16);
    return res;
}

__global__ __launch_bounds__(256) void sobel_kernel(const float* __restrict__ x,
                                                    float* __restrict__ out) {
    const int lane = threadIdx.x & 63;
    const int wave = threadIdx.x >> 6;
    const int r0   = blockIdx.x * TILE_ROWS + wave * ROWS_PT;

    const float* img = x   + (size_t)blockIdx.y * (IMG_H * IMG_W);
    float*       o   = out + (size_t)blockIdx.y * (IMG_H * IMG_W);

    Row A = load_row(img, r0 - 1, lane);
    Row B = load_row(img, r0,     lane);

#pragma unroll
    for (int i = 0; i < ROWS_PT; ++i) {
        const int r = r0 + i;
        Row C = load_row(img, r + 1, lane);

        vfloat4 ra = sobel_half(A.a, A.la, A.ra, B.a, B.la, B.ra, C.a, C.la, C.ra);
        vfloat4 rb = sobel_half(A.b, A.lb, A.rb, B.b, B.lb, B.rb, C.b, C.lb, C.rb);

        float* po = o + (size_t)r * IMG_W + 4 * lane;
        // Output is never re-read: nontemporal stores keep input halo lines in L1/L2.
        __builtin_nontemporal_store(ra, reinterpret_cast<vfloat4*>(po));
        __builtin_nontemporal_store(rb, reinterpret_cast<vfloat4*>(po + 256));

        A = B; B = C;   // slide window down one row
    }
}

extern "C" void kernel_launch(void* const* d_in, const int* in_sizes, int n_in,
                              void* d_out, int out_size, void* d_ws, size_t ws_size,
                              hipStream_t stream) {
    const float* x = (const float*)d_in[0];
    float* out = (float*)d_out;
    const int batch = in_sizes[0] / (IMG_H * IMG_W);   // 64
    dim3 grid(IMG_H / TILE_ROWS, batch);               // (32, 64) = 2048 blocks
    sobel_kernel<<<grid, 256, 0, stream>>>(x, out);
}